// Round 1
// baseline (13510.004 us; speedup 1.0000x reference)
//
#include <hip/hip_runtime.h>
#include <hip/hip_bf16.h>

#define NN 50000
#define TT 48
#define HD 256
#define FIN 11
#define KAUG 288   // 256 (H) + 11 (X) + 21 pad zeros, multiple of 32
#define LDP 40     // LDS row pitch (bf16) to break bank conflicts
#define HSP 264    // hs row pitch (bf16), 264*2 % 16 == 0

typedef __bf16 bf16_t;
typedef __bf16 v8bf __attribute__((ext_vector_type(8)));
typedef float v4f __attribute__((ext_vector_type(4)));

__device__ __forceinline__ float sigmoidf_(float x) {
  return 1.0f / (1.0f + __expf(-x));
}

// ---------------- weight packing (bf16, augmented K) ----------------
// Bzr[512][288]: rows 0..255 -> [Wh0 | Wx0 | 0], rows 256..511 -> [Wh1 | Wx1 | 0]
// Bh [256][288]: [Wh2 | Wx2 | 0]
// Bu [1024][256]: uWx gate0, uWx gate2, spWx gate0, spWx gate2
__global__ void pack_w(const float* __restrict__ bbWx, const float* __restrict__ bbWh,
                       const float* __restrict__ uWx, const float* __restrict__ spWx,
                       bf16_t* __restrict__ Bzr, bf16_t* __restrict__ Bh,
                       bf16_t* __restrict__ Bu) {
  int i0 = blockIdx.x * blockDim.x + threadIdx.x;
  int stride = gridDim.x * blockDim.x;
  for (int idx = i0; idx < 512 * KAUG; idx += stride) {
    int n = idx / KAUG, k = idx - n * KAUG;
    int g = n >> 8, nn = n & 255;
    float v = 0.0f;
    if (k < 256) v = bbWh[(g * 256 + nn) * 256 + k];
    else if (k < 267) v = bbWx[(g * 256 + nn) * FIN + (k - 256)];
    Bzr[idx] = (bf16_t)v;
  }
  for (int idx = i0; idx < 256 * KAUG; idx += stride) {
    int n = idx / KAUG, k = idx - n * KAUG;
    float v = 0.0f;
    if (k < 256) v = bbWh[(512 + n) * 256 + k];
    else if (k < 267) v = bbWx[(512 + n) * FIN + (k - 256)];
    Bh[idx] = (bf16_t)v;
  }
  for (int idx = i0; idx < 1024 * 256; idx += stride) {
    int n = idx >> 8, k = idx & 255;
    int g = n >> 8, nn = n & 255;
    const float* W = (g < 2) ? uWx : spWx;
    int gate = (g & 1) ? 2 : 0;
    Bu[idx] = (bf16_t)W[(gate * 256 + nn) * 256 + k];
  }
}

// Haug[m] = [H0=0 (256) | X_0[m] (11) | 0 pad (21)]
__global__ void init_h(const float* __restrict__ X, bf16_t* __restrict__ Haug) {
  int i0 = blockIdx.x * blockDim.x + threadIdx.x;
  int stride = gridDim.x * blockDim.x;
  for (int idx = i0; idx < NN * KAUG; idx += stride) {
    int m = idx / KAUG, k = idx - m * KAUG;
    float v = 0.0f;
    if (k >= 256 && k < 267) v = X[m * FIN + (k - 256)];
    Haug[idx] = (bf16_t)v;
  }
}

// ---------------- K1: z,r gates.  C[64x256] per block, blockIdx.y: 0=z 1=r ---
__global__ __launch_bounds__(256) void gemm_zr(
    const bf16_t* __restrict__ Haug, const bf16_t* __restrict__ Bzr,
    const float* __restrict__ bbx, const float* __restrict__ bbh,
    bf16_t* __restrict__ Zbuf, bf16_t* __restrict__ rHaug) {
  __shared__ __align__(16) bf16_t As[64 * LDP];
  __shared__ __align__(16) bf16_t Bs[256 * LDP];
  const int tid = threadIdx.x;
  const int lane15 = tid & 15, quad = (tid & 63) >> 4, wave = tid >> 6;
  const int rowBase = blockIdx.x * 64;
  const int g = blockIdx.y;  // 0=z, 1=r
  v4f acc[4][4] = {};

  const int arow = tid >> 2;
  const int acg = (tid & 3) * 8;
  const bool aok = (rowBase + arow) < NN;
  const bf16_t* aptr = Haug + (long)(rowBase + arow) * KAUG + acg;
  const bf16_t* bbase = Bzr + (long)(g * 256) * KAUG;

  for (int kt = 0; kt < KAUG / 32; ++kt) {
    const int k0 = kt * 32;
    uint4 av = make_uint4(0u, 0u, 0u, 0u);
    if (aok) av = *(const uint4*)(aptr + k0);
    *(uint4*)(As + arow * LDP + acg) = av;
#pragma unroll
    for (int u = 0; u < 4; ++u) {
      int id = u * 256 + tid;
      int br = id >> 2, seg = (id & 3) * 8;
      *(uint4*)(Bs + br * LDP + seg) = *(const uint4*)(bbase + (long)br * KAUG + k0 + seg);
    }
    __syncthreads();
    v8bf a[4], b[4];
#pragma unroll
    for (int mf = 0; mf < 4; ++mf)
      a[mf] = *(const v8bf*)(As + (mf * 16 + lane15) * LDP + quad * 8);
#pragma unroll
    for (int nf = 0; nf < 4; ++nf)
      b[nf] = *(const v8bf*)(Bs + (wave * 64 + nf * 16 + lane15) * LDP + quad * 8);
#pragma unroll
    for (int mf = 0; mf < 4; ++mf)
#pragma unroll
      for (int nf = 0; nf < 4; ++nf)
        acc[mf][nf] = __builtin_amdgcn_mfma_f32_16x16x32_bf16(a[mf], b[nf], acc[mf][nf], 0, 0, 0);
    __syncthreads();
  }

#pragma unroll
  for (int nf = 0; nf < 4; ++nf) {
    const int col = wave * 64 + nf * 16 + lane15;  // 0..255
    const float bias = bbx[g * 256 + col] + bbh[g * 256 + col];
#pragma unroll
    for (int mf = 0; mf < 4; ++mf) {
#pragma unroll
      for (int reg = 0; reg < 4; ++reg) {
        const int m = rowBase + mf * 16 + quad * 4 + reg;
        if (m >= NN) continue;
        const float sg = sigmoidf_(acc[mf][nf][reg] + bias);
        if (g == 0) {
          Zbuf[(long)m * HD + col] = (bf16_t)sg;
        } else {
          const float hp = (float)Haug[(long)m * KAUG + col];
          rHaug[(long)m * KAUG + col] = (bf16_t)(sg * hp);
        }
      }
    }
  }
  // r-blocks also copy the X (+pad) columns into rHaug for the h-tilde gemm
  if (g == 1) {
    const int row = tid >> 2, cb = 256 + (tid & 3) * 8;
    const int m = rowBase + row;
    if (m < NN)
      *(uint4*)(rHaug + (long)m * KAUG + cb) = *(const uint4*)(Haug + (long)m * KAUG + cb);
  }
}

// ---------------- K2: h_tilde + Hn update + stage X_{t+1} -------------------
__global__ __launch_bounds__(256) void gemm_h(
    const bf16_t* __restrict__ rHaug, const bf16_t* __restrict__ Bh,
    const float* __restrict__ bbx, const float* __restrict__ bbh,
    const bf16_t* __restrict__ Zbuf, const float* __restrict__ Xseq, int t,
    bf16_t* __restrict__ Haug) {
  __shared__ __align__(16) bf16_t As[64 * LDP];
  __shared__ __align__(16) bf16_t Bs[256 * LDP];
  const int tid = threadIdx.x;
  const int lane15 = tid & 15, quad = (tid & 63) >> 4, wave = tid >> 6;
  const int rowBase = blockIdx.x * 64;
  v4f acc[4][4] = {};

  const int arow = tid >> 2;
  const int acg = (tid & 3) * 8;
  const bool aok = (rowBase + arow) < NN;
  const bf16_t* aptr = rHaug + (long)(rowBase + arow) * KAUG + acg;

  for (int kt = 0; kt < KAUG / 32; ++kt) {
    const int k0 = kt * 32;
    uint4 av = make_uint4(0u, 0u, 0u, 0u);
    if (aok) av = *(const uint4*)(aptr + k0);
    *(uint4*)(As + arow * LDP + acg) = av;
#pragma unroll
    for (int u = 0; u < 4; ++u) {
      int id = u * 256 + tid;
      int br = id >> 2, seg = (id & 3) * 8;
      *(uint4*)(Bs + br * LDP + seg) = *(const uint4*)(Bh + (long)br * KAUG + k0 + seg);
    }
    __syncthreads();
    v8bf a[4], b[4];
#pragma unroll
    for (int mf = 0; mf < 4; ++mf)
      a[mf] = *(const v8bf*)(As + (mf * 16 + lane15) * LDP + quad * 8);
#pragma unroll
    for (int nf = 0; nf < 4; ++nf)
      b[nf] = *(const v8bf*)(Bs + (wave * 64 + nf * 16 + lane15) * LDP + quad * 8);
#pragma unroll
    for (int mf = 0; mf < 4; ++mf)
#pragma unroll
      for (int nf = 0; nf < 4; ++nf)
        acc[mf][nf] = __builtin_amdgcn_mfma_f32_16x16x32_bf16(a[mf], b[nf], acc[mf][nf], 0, 0, 0);
    __syncthreads();
  }

#pragma unroll
  for (int nf = 0; nf < 4; ++nf) {
    const int n = wave * 64 + nf * 16 + lane15;  // 0..255
    const float bias = bbx[512 + n] + bbh[512 + n];
#pragma unroll
    for (int mf = 0; mf < 4; ++mf) {
#pragma unroll
      for (int reg = 0; reg < 4; ++reg) {
        const int m = rowBase + mf * 16 + quad * 4 + reg;
        if (m >= NN) continue;
        const float htl = tanhf(acc[mf][nf][reg] + bias);
        const float z = (float)Zbuf[(long)m * HD + n];
        const float hp = (float)Haug[(long)m * KAUG + n];
        Haug[(long)m * KAUG + n] = (bf16_t)(z * hp + (1.0f - z) * htl);
      }
    }
  }
  // stage X_{t+1} into the augmented columns (pads stay 0 from init)
  {
    const int row = tid >> 2, jj = tid & 3;
    const int m = rowBase + row;
    if (m < NN) {
      for (int j = jj; j < FIN; j += 4) {
        float xv = 0.0f;
        if (t + 1 < TT) xv = Xseq[((long)(t + 1) * NN + m) * FIN + j];
        Haug[(long)m * KAUG + 256 + j] = (bf16_t)xv;
      }
    }
  }
}

// ---------------- K3: gru_u / gru_sp gates (H=None => only 2 gemms each) ----
// C[64x512] per block: paired column strips so (z-gate, h-gate) land in the
// same wave; heads fused via LDS so hu/hp never hit HBM.
__global__ __launch_bounds__(256) void gemm_heads(
    const bf16_t* __restrict__ Haug, const bf16_t* __restrict__ Bu,
    const float* __restrict__ ubx, const float* __restrict__ ubh,
    const float* __restrict__ spbx, const float* __restrict__ spbh,
    const float* __restrict__ Wu, const float* __restrict__ buv,
    const float* __restrict__ Ws, const float* __restrict__ bsv,
    const float* __restrict__ Wp, const float* __restrict__ bpv,
    float* __restrict__ out, int t) {
  __shared__ __align__(16) bf16_t As[64 * LDP];
  __shared__ __align__(16) bf16_t Bs[512 * LDP];
  const int tid = threadIdx.x;
  const int lane15 = tid & 15, quad = (tid & 63) >> 4, wave = tid >> 6;
  const int rowBase = blockIdx.x * 64;
  const int half = blockIdx.y;  // 0: gru_u (U head), 1: gru_sp (S,P heads)
  v4f acc[4][8] = {};

  const int arow = tid >> 2;
  const int acg = (tid & 3) * 8;
  const bool aok = (rowBase + arow) < NN;
  const bf16_t* aptr = Haug + (long)(rowBase + arow) * KAUG + acg;  // K=256 of 288
  const bf16_t* bbase = Bu + (long)(half * 512) * 256;

  for (int kt = 0; kt < 8; ++kt) {
    const int k0 = kt * 32;
    uint4 av = make_uint4(0u, 0u, 0u, 0u);
    if (aok) av = *(const uint4*)(aptr + k0);
    *(uint4*)(As + arow * LDP + acg) = av;
#pragma unroll
    for (int u = 0; u < 8; ++u) {
      int id = u * 256 + tid;
      int br = id >> 2, seg = (id & 3) * 8;
      *(uint4*)(Bs + br * LDP + seg) = *(const uint4*)(bbase + (long)br * 256 + k0 + seg);
    }
    __syncthreads();
    v8bf a[4], b[8];
#pragma unroll
    for (int mf = 0; mf < 4; ++mf)
      a[mf] = *(const v8bf*)(As + (mf * 16 + lane15) * LDP + quad * 8);
#pragma unroll
    for (int nf = 0; nf < 8; ++nf) {
      const int nlocal = (nf < 4) ? (wave * 64 + nf * 16) : (256 + wave * 64 + (nf - 4) * 16);
      b[nf] = *(const v8bf*)(Bs + (nlocal + lane15) * LDP + quad * 8);
    }
#pragma unroll
    for (int mf = 0; mf < 4; ++mf)
#pragma unroll
      for (int nf = 0; nf < 8; ++nf)
        acc[mf][nf] = __builtin_amdgcn_mfma_f32_16x16x32_bf16(a[mf], b[nf], acc[mf][nf], 0, 0, 0);
    __syncthreads();
  }

  const float* bx = half ? spbx : ubx;
  const float* bh = half ? spbh : ubh;
  bf16_t* hs = Bs;  // reuse B LDS: 64 x HSP bf16 = 33792 B <= 40960 B

#pragma unroll
  for (int nf = 0; nf < 4; ++nf) {
    const int j = wave * 64 + nf * 16 + lane15;  // 0..255
    const float b0 = bx[j] + bh[j];              // gate z
    const float b1 = bx[512 + j] + bh[512 + j];  // gate h (index 2)
#pragma unroll
    for (int mf = 0; mf < 4; ++mf) {
#pragma unroll
      for (int reg = 0; reg < 4; ++reg) {
        const int r = mf * 16 + quad * 4 + reg;
        const float zz = sigmoidf_(acc[mf][nf][reg] + b0);
        const float ht = tanhf(acc[mf][nf + 4][reg] + b1);
        hs[r * HSP + j] = (bf16_t)((1.0f - zz) * ht);  // (1-z)*h_tilde
      }
    }
  }
  __syncthreads();

  if (half == 0) {
    for (int o = tid; o < 64 * 3; o += 256) {
      const int r = o / 3, k = o - r * 3;
      const int m = rowBase + r;
      if (m < NN) {
        float s = 0.0f;
        for (int j = 0; j < 256; j += 8) {
          v8bf hv = *(const v8bf*)(hs + r * HSP + j);
#pragma unroll
          for (int jj = 0; jj < 8; ++jj) s += (float)hv[jj] * Wu[k * 256 + j + jj];
        }
        out[(long)t * (NN * 3) + (long)m * 3 + k] = s + buv[k];
      }
    }
  } else {
    for (int o = tid; o < 128; o += 256) {
      const int r = o >> 1, which = o & 1;  // 0: S, 1: P
      const int m = rowBase + r;
      if (m < NN) {
        const float* W = which ? Wp : Ws;
        float s = 0.0f;
        for (int j = 0; j < 256; j += 8) {
          v8bf hv = *(const v8bf*)(hs + r * HSP + j);
#pragma unroll
          for (int jj = 0; jj < 8; ++jj) s += (float)hv[jj] * W[j + jj];
        }
        s += which ? bpv[0] : bsv[0];
        const long base = (long)TT * NN * 3 + (long)which * TT * NN + (long)t * NN + m;
        out[base] = s;
      }
    }
  }
}

extern "C" void kernel_launch(void* const* d_in, const int* in_sizes, int n_in,
                              void* d_out, int out_size, void* d_ws, size_t ws_size,
                              hipStream_t stream) {
  const float* X    = (const float*)d_in[0];
  // d_in[1] edge_index: unused (ChebConv K=1 ignores edges)
  const float* bbWx = (const float*)d_in[2];
  const float* bbbx = (const float*)d_in[3];
  const float* bbWh = (const float*)d_in[4];
  const float* bbbh = (const float*)d_in[5];
  const float* uWx  = (const float*)d_in[6];
  const float* ubx  = (const float*)d_in[7];
  const float* ubh  = (const float*)d_in[9];   // u_Wh (d_in[8]) is dead: H=None
  const float* spWx = (const float*)d_in[10];
  const float* spbx = (const float*)d_in[11];
  const float* spbh = (const float*)d_in[13];  // sp_Wh (d_in[12]) dead
  const float* Wu   = (const float*)d_in[14];
  const float* buv  = (const float*)d_in[15];
  const float* Ws   = (const float*)d_in[16];
  const float* bsv  = (const float*)d_in[17];
  const float* Wp   = (const float*)d_in[18];
  const float* bpv  = (const float*)d_in[19];
  float* out = (float*)d_out;

  char* ws = (char*)d_ws;
  // all offsets 16B-aligned
  bf16_t* Haug  = (bf16_t*)(ws);                 // 50000*288*2 = 28,800,000
  bf16_t* rHaug = (bf16_t*)(ws + 28800000);      // 28,800,000
  bf16_t* Zbuf  = (bf16_t*)(ws + 57600000);      // 50000*256*2 = 25,600,000
  bf16_t* Bzr   = (bf16_t*)(ws + 83200000);      // 512*288*2 = 294,912
  bf16_t* Bh    = (bf16_t*)(ws + 83494912);      // 256*288*2 = 147,456
  bf16_t* Bu    = (bf16_t*)(ws + 83642368);      // 1024*256*2 = 524,288
  if (ws_size < (size_t)84166656) return;        // need ~84.2 MB scratch

  pack_w<<<dim3(192), dim3(256), 0, stream>>>(bbWx, bbWh, uWx, spWx, Bzr, Bh, Bu);
  init_h<<<dim3(1024), dim3(256), 0, stream>>>(X, Haug);

  const int MB = (NN + 63) / 64;  // 782
  for (int t = 0; t < TT; ++t) {
    gemm_zr<<<dim3(MB, 2), dim3(256), 0, stream>>>(Haug, Bzr, bbbx, bbbh, Zbuf, rHaug);
    gemm_h<<<dim3(MB), dim3(256), 0, stream>>>(rHaug, Bh, bbbx, bbbh, Zbuf, X, t, Haug);
    gemm_heads<<<dim3(MB, 2), dim3(256), 0, stream>>>(Haug, Bu, ubx, ubh, spbx, spbh,
                                                      Wu, buv, Ws, bsv, Wp, bpv, out, t);
  }
}